// Round 1
// baseline (1284.535 us; speedup 1.0000x reference)
//
#include <hip/hip_runtime.h>
#include <hip/hip_bf16.h>

// truncated_krylov_layer: out = concat(X, AX, ..., A^7 X) @ W + b
// Strategy:
//  - Build CSR by dst (count / scan / fill) in workspace each launch.
//  - 7 SpMM passes, wave-per-dst-row, float2 per lane (128 floats/row),
//    cooperative edge load + __shfl broadcast, 4-edge unroll for MLP.
//  - GEMM fused as 8 accumulating K=128 fp32 GEMMs: out (+)= X_i @ W_i
//    (term 0 reads the input directly; terms ping-pong in workspace).

#define F 128  // feature dim (in and out), hardcoded per problem

// ---------------- CSR build ----------------

__global__ __launch_bounds__(256) void count_kernel(const int* __restrict__ dst,
                                                    int* __restrict__ counts, int E) {
    int e = blockIdx.x * 256 + threadIdx.x;
    if (e < E) atomicAdd(&counts[dst[e]], 1);
}

__global__ __launch_bounds__(256) void scan_partial(const int* __restrict__ counts,
                                                    int* __restrict__ partials, int n) {
    __shared__ int sm[256];
    int tid = threadIdx.x;
    int i = blockIdx.x * 256 + tid;
    sm[tid] = (i < n) ? counts[i] : 0;
    __syncthreads();
    for (int off = 128; off > 0; off >>= 1) {
        if (tid < off) sm[tid] += sm[tid + off];
        __syncthreads();
    }
    if (tid == 0) partials[blockIdx.x] = sm[0];
}

__global__ __launch_bounds__(64) void scan_root(int* __restrict__ partials, int nb) {
    int lane = threadIdx.x;
    int run = 0;
    for (int base = 0; base < nb; base += 64) {
        int i = base + lane;
        int v = (i < nb) ? partials[i] : 0;
        int orig = v;
        for (int off = 1; off < 64; off <<= 1) {
            int t = __shfl_up(v, off, 64);
            if (lane >= off) v += t;
        }
        if (i < nb) partials[i] = run + v - orig;  // exclusive
        run += __shfl(v, 63, 64);
    }
}

__global__ __launch_bounds__(256) void scan_final(const int* __restrict__ counts,
                                                  const int* __restrict__ partials,
                                                  int* __restrict__ offsets,
                                                  int* __restrict__ cursor, int n) {
    __shared__ int sm[256];
    int tid = threadIdx.x;
    int i = blockIdx.x * 256 + tid;
    int v = (i < n) ? counts[i] : 0;
    sm[tid] = v;
    __syncthreads();
    for (int off = 1; off < 256; off <<= 1) {
        int t = (tid >= off) ? sm[tid - off] : 0;
        __syncthreads();
        sm[tid] += t;
        __syncthreads();
    }
    int incl = sm[tid];
    int base = partials[blockIdx.x];
    if (i < n) {
        offsets[i + 1] = base + incl;
        cursor[i] = base + incl - v;
    }
    if (i == 0) offsets[0] = 0;
}

__global__ __launch_bounds__(256) void fill_kernel(const int* __restrict__ src,
                                                   const int* __restrict__ dst,
                                                   const float* __restrict__ w,
                                                   int* __restrict__ cursor,
                                                   int* __restrict__ ssrc,
                                                   float* __restrict__ swt, int E) {
    int e = blockIdx.x * 256 + threadIdx.x;
    if (e < E) {
        int d = dst[e];
        int pos = atomicAdd(&cursor[d], 1);
        ssrc[pos] = src[e];
        swt[pos] = w[e];
    }
}

// ---------------- SpMM: one wave per dst row ----------------

__global__ __launch_bounds__(256) void spmm_kernel(const int* __restrict__ offs,
                                                   const int* __restrict__ ssrc,
                                                   const float* __restrict__ swt,
                                                   const float* __restrict__ Xin,
                                                   float* __restrict__ Xout, int n) {
    int gw = (int)((blockIdx.x * 256 + threadIdx.x) >> 6);
    int lane = threadIdx.x & 63;
    if (gw >= n) return;
    int s0 = offs[gw], s1 = offs[gw + 1];
    const float2* X2 = (const float2*)Xin;
    float accx = 0.f, accy = 0.f;
    for (int base = s0; base < s1; base += 64) {
        int cnt = min(s1 - base, 64);
        int sv = 0;
        float wv = 0.f;
        if (lane < cnt) {
            sv = ssrc[base + lane];
            wv = swt[base + lane];
        }
        int j = 0;
        int jm = cnt & ~3;
        for (; j < jm; j += 4) {
            int a0 = __shfl(sv, j, 64), a1 = __shfl(sv, j + 1, 64);
            int a2 = __shfl(sv, j + 2, 64), a3 = __shfl(sv, j + 3, 64);
            float w0 = __shfl(wv, j, 64), w1 = __shfl(wv, j + 1, 64);
            float w2 = __shfl(wv, j + 2, 64), w3 = __shfl(wv, j + 3, 64);
            float2 x0 = X2[(size_t)a0 * 64 + lane];
            float2 x1 = X2[(size_t)a1 * 64 + lane];
            float2 x2 = X2[(size_t)a2 * 64 + lane];
            float2 x3 = X2[(size_t)a3 * 64 + lane];
            accx += w0 * x0.x; accy += w0 * x0.y;
            accx += w1 * x1.x; accy += w1 * x1.y;
            accx += w2 * x2.x; accy += w2 * x2.y;
            accx += w3 * x3.x; accy += w3 * x3.y;
        }
        for (; j < cnt; ++j) {
            int a = __shfl(sv, j, 64);
            float wj = __shfl(wv, j, 64);
            float2 x = X2[(size_t)a * 64 + lane];
            accx += wj * x.x; accy += wj * x.y;
        }
    }
    float2 r;
    r.x = accx; r.y = accy;
    ((float2*)Xout)[(size_t)gw * 64 + lane] = r;
}

// ---------------- fp32 GEMM accumulate: out (+)= T[n,128] @ Wb[128,128] ----------------
// block tile: 128 rows x 128 cols, 256 threads, 8x8 micro-tile per thread.

__global__ __launch_bounds__(256) void gemm128(const float* __restrict__ T,
                                               const float* __restrict__ Wb,
                                               const float* __restrict__ bias,
                                               float* __restrict__ out, int n, int first) {
    __shared__ float Ash[128][17];
    __shared__ float Bsh[16][128];
    int tid = threadIdx.x;
    int tx = tid & 15;   // col group: cols f = tx + 16*ci
    int ty = tid >> 4;   // row group: rows r = ty*8 + ri
    int n0 = blockIdx.x * 128;

    float acc[8][8];
#pragma unroll
    for (int i = 0; i < 8; i++)
#pragma unroll
        for (int j = 0; j < 8; j++) acc[i][j] = 0.f;

    for (int kk = 0; kk < 128; kk += 16) {
        // load A tile (128x16)
#pragma unroll
        for (int j = 0; j < 8; j++) {
            int idx = tid + 256 * j;           // 0..2047
            int r = idx >> 4, c = idx & 15;
            int gr = n0 + r;
            Ash[r][c] = (gr < n) ? T[(size_t)gr * F + kk + c] : 0.f;
        }
        // load B tile (16x128)
#pragma unroll
        for (int j = 0; j < 8; j++) {
            int idx = tid + 256 * j;
            int k = idx >> 7, f = idx & 127;
            Bsh[k][f] = Wb[(size_t)(kk + k) * F + f];
        }
        __syncthreads();
#pragma unroll
        for (int k = 0; k < 16; k++) {
            float a[8], b[8];
#pragma unroll
            for (int ri = 0; ri < 8; ri++) a[ri] = Ash[ty * 8 + ri][k];
#pragma unroll
            for (int ci = 0; ci < 8; ci++) b[ci] = Bsh[k][tx + 16 * ci];
#pragma unroll
            for (int ri = 0; ri < 8; ri++)
#pragma unroll
                for (int ci = 0; ci < 8; ci++) acc[ri][ci] += a[ri] * b[ci];
        }
        __syncthreads();
    }

#pragma unroll
    for (int ri = 0; ri < 8; ri++) {
        int gr = n0 + ty * 8 + ri;
        if (gr < n) {
#pragma unroll
            for (int ci = 0; ci < 8; ci++) {
                int f = tx + 16 * ci;
                float base = first ? bias[f] : out[(size_t)gr * F + f];
                out[(size_t)gr * F + f] = base + acc[ri][ci];
            }
        }
    }
}

// ---------------- launch ----------------

extern "C" void kernel_launch(void* const* d_in, const int* in_sizes, int n_in,
                              void* d_out, int out_size, void* d_ws, size_t ws_size,
                              hipStream_t stream) {
    const float* input = (const float*)d_in[0];
    const int* esrc = (const int*)d_in[1];
    const int* edst = (const int*)d_in[2];
    const float* ew = (const float*)d_in[3];
    const float* SW = (const float*)d_in[4];
    const float* bias = (const float*)d_in[5];
    float* out = (float*)d_out;

    int N = in_sizes[0] / F;
    int E = in_sizes[1];

    // workspace carve-up (256B aligned)
    size_t off = 0;
    auto take = [&](size_t bytes) -> void* {
        void* p = (char*)d_ws + off;
        off += (bytes + 255) & ~(size_t)255;
        return p;
    };
    int* counts = (int*)take((size_t)N * 4);
    int* offsets = (int*)take((size_t)(N + 1) * 4);
    int* cursor = (int*)take((size_t)N * 4);
    int* partials = (int*)take(4096);
    int* ssrc = (int*)take((size_t)E * 4);
    float* swt = (float*)take((size_t)E * 4);
    float* ping = (float*)take((size_t)N * F * 4);
    float* pong = (float*)take((size_t)N * F * 4);
    (void)ws_size;

    hipMemsetAsync(counts, 0, (size_t)N * 4, stream);

    int eb = (E + 255) / 256;
    int nb = (N + 255) / 256;
    count_kernel<<<eb, 256, 0, stream>>>(edst, counts, E);
    scan_partial<<<nb, 256, 0, stream>>>(counts, partials, N);
    scan_root<<<1, 64, 0, stream>>>(partials, nb);
    scan_final<<<nb, 256, 0, stream>>>(counts, partials, offsets, cursor, N);
    fill_kernel<<<eb, 256, 0, stream>>>(esrc, edst, ew, cursor, ssrc, swt, E);

    int gemm_blocks = (N + 127) / 128;
    int spmm_blocks = (N + 3) / 4;

    // term 0: out = bias + input @ W0
    gemm128<<<gemm_blocks, 256, 0, stream>>>(input, SW, bias, out, N, 1);

    const float* cur = input;
    float* bufs[2] = {ping, pong};
    for (int i = 1; i < 8; i++) {
        float* nxt = bufs[(i - 1) & 1];
        spmm_kernel<<<spmm_blocks, 256, 0, stream>>>(offsets, ssrc, swt, cur, nxt, N);
        gemm128<<<gemm_blocks, 256, 0, stream>>>(nxt, SW + (size_t)i * F * F, bias, out, N, 0);
        cur = nxt;
    }
}

// Round 2
// 736.148 us; speedup vs baseline: 1.7449x; 1.7449x over previous
//
#include <hip/hip_runtime.h>
#include <hip/hip_bf16.h>

// truncated_krylov_layer: out = concat(X, AX, ..., A^7 X) @ W + b
//  - CSR-by-dst build (count/scan/fill) in workspace.
//  - 7 SpMM passes, wave-per-dst-row, float2/lane, shfl-broadcast edges.
//  - GEMM: single K=1024 fp32 GEMM over all 8 materialized terms
//    (fallback: per-term accumulating GEMM if ws_size too small).
//    128x128 tile, 256 thr, 8x8 micro-tile, k-major A in LDS, b128 frags,
//    register-prefetch software pipeline.

#define F 128

// ---------------- CSR build ----------------

__global__ __launch_bounds__(256) void count_kernel(const int* __restrict__ dst,
                                                    int* __restrict__ counts, int E) {
    int e = blockIdx.x * 256 + threadIdx.x;
    if (e < E) atomicAdd(&counts[dst[e]], 1);
}

__global__ __launch_bounds__(256) void scan_partial(const int* __restrict__ counts,
                                                    int* __restrict__ partials, int n) {
    __shared__ int sm[256];
    int tid = threadIdx.x;
    int i = blockIdx.x * 256 + tid;
    sm[tid] = (i < n) ? counts[i] : 0;
    __syncthreads();
    for (int off = 128; off > 0; off >>= 1) {
        if (tid < off) sm[tid] += sm[tid + off];
        __syncthreads();
    }
    if (tid == 0) partials[blockIdx.x] = sm[0];
}

__global__ __launch_bounds__(64) void scan_root(int* __restrict__ partials, int nb) {
    int lane = threadIdx.x;
    int run = 0;
    for (int base = 0; base < nb; base += 64) {
        int i = base + lane;
        int v = (i < nb) ? partials[i] : 0;
        int orig = v;
        for (int off = 1; off < 64; off <<= 1) {
            int t = __shfl_up(v, off, 64);
            if (lane >= off) v += t;
        }
        if (i < nb) partials[i] = run + v - orig;  // exclusive
        run += __shfl(v, 63, 64);
    }
}

__global__ __launch_bounds__(256) void scan_final(const int* __restrict__ counts,
                                                  const int* __restrict__ partials,
                                                  int* __restrict__ offsets,
                                                  int* __restrict__ cursor, int n) {
    __shared__ int sm[256];
    int tid = threadIdx.x;
    int i = blockIdx.x * 256 + tid;
    int v = (i < n) ? counts[i] : 0;
    sm[tid] = v;
    __syncthreads();
    for (int off = 1; off < 256; off <<= 1) {
        int t = (tid >= off) ? sm[tid - off] : 0;
        __syncthreads();
        sm[tid] += t;
        __syncthreads();
    }
    int incl = sm[tid];
    int base = partials[blockIdx.x];
    if (i < n) {
        offsets[i + 1] = base + incl;
        cursor[i] = base + incl - v;
    }
    if (i == 0) offsets[0] = 0;
}

__global__ __launch_bounds__(256) void fill_kernel(const int* __restrict__ src,
                                                   const int* __restrict__ dst,
                                                   const float* __restrict__ w,
                                                   int* __restrict__ cursor,
                                                   int* __restrict__ ssrc,
                                                   float* __restrict__ swt, int E) {
    int e = blockIdx.x * 256 + threadIdx.x;
    if (e < E) {
        int d = dst[e];
        int pos = atomicAdd(&cursor[d], 1);
        ssrc[pos] = src[e];
        swt[pos] = w[e];
    }
}

// ---------------- SpMM: one wave per dst row ----------------

__global__ __launch_bounds__(256) void spmm_kernel(const int* __restrict__ offs,
                                                   const int* __restrict__ ssrc,
                                                   const float* __restrict__ swt,
                                                   const float* __restrict__ Xin,
                                                   float* __restrict__ Xout, int n) {
    int gw = (int)((blockIdx.x * 256 + threadIdx.x) >> 6);
    int lane = threadIdx.x & 63;
    if (gw >= n) return;
    int s0 = offs[gw], s1 = offs[gw + 1];
    const float2* X2 = (const float2*)Xin;
    float accx = 0.f, accy = 0.f;
    for (int base = s0; base < s1; base += 64) {
        int cnt = min(s1 - base, 64);
        int sv = 0;
        float wv = 0.f;
        if (lane < cnt) {
            sv = ssrc[base + lane];
            wv = swt[base + lane];
        }
        int j = 0;
        int jm = cnt & ~3;
        for (; j < jm; j += 4) {
            int a0 = __shfl(sv, j, 64), a1 = __shfl(sv, j + 1, 64);
            int a2 = __shfl(sv, j + 2, 64), a3 = __shfl(sv, j + 3, 64);
            float w0 = __shfl(wv, j, 64), w1 = __shfl(wv, j + 1, 64);
            float w2 = __shfl(wv, j + 2, 64), w3 = __shfl(wv, j + 3, 64);
            float2 x0 = X2[(size_t)a0 * 64 + lane];
            float2 x1 = X2[(size_t)a1 * 64 + lane];
            float2 x2 = X2[(size_t)a2 * 64 + lane];
            float2 x3 = X2[(size_t)a3 * 64 + lane];
            accx += w0 * x0.x; accy += w0 * x0.y;
            accx += w1 * x1.x; accy += w1 * x1.y;
            accx += w2 * x2.x; accy += w2 * x2.y;
            accx += w3 * x3.x; accy += w3 * x3.y;
        }
        for (; j < cnt; ++j) {
            int a = __shfl(sv, j, 64);
            float wj = __shfl(wv, j, 64);
            float2 x = X2[(size_t)a * 64 + lane];
            accx += wj * x.x; accy += wj * x.y;
        }
    }
    float2 r;
    r.x = accx; r.y = accy;
    ((float2*)Xout)[(size_t)gw * 64 + lane] = r;
}

// ---------------- fp32 GEMM over nterms concatenated K=128 slices ----------------
// out[n,128] (+)= sum_i T_i[n,128] @ W_(term0+i)[128,128]   (+ bias if first)
// 128x128 block tile, 256 threads, 8x8 micro-tile.
// LDS: A stored k-major (AshT[k][r]) so both frags are contiguous b128 reads.

struct TPtrs { const float* t[8]; };

__global__ __launch_bounds__(256) void gemm_multi(TPtrs tp, int nterms, int term0,
                                                  const float* __restrict__ SW,
                                                  const float* __restrict__ bias,
                                                  float* __restrict__ out, int n, int first) {
    __shared__ float AshT[16][128];
    __shared__ float Bsh[16][128];
    int tid = threadIdx.x;
    int tx = tid & 15;   // cols tx*8 .. tx*8+7
    int ty = tid >> 4;   // rows ty*8 .. ty*8+7
    int n0 = blockIdx.x * 128;

    // A staging mapping: row ar, 8 cols starting at ac (within 16-wide slice)
    int ar = tid >> 1;
    int ac = (tid & 1) * 8;
    int agr = n0 + ar;
    bool aval = agr < n;
    // B staging mapping: k-row bk, 8 cols at bf
    int bk = tid >> 4;
    int bf = (tid & 15) * 8;

    float acc[8][8];
#pragma unroll
    for (int i = 0; i < 8; i++)
#pragma unroll
        for (int j = 0; j < 8; j++) acc[i][j] = 0.f;

    int nS = nterms * 8;  // number of 16-wide K slices

    float4 av0, av1, bv0, bv1;
    // prefetch slice 0
    {
        const float* T = tp.t[0];
        if (aval) {
            const float* p = T + (size_t)agr * F + ac;
            av0 = *(const float4*)p;
            av1 = *(const float4*)(p + 4);
        } else {
            av0 = make_float4(0.f, 0.f, 0.f, 0.f);
            av1 = av0;
        }
        const float* q = SW + (size_t)term0 * F * F + (size_t)bk * F + bf;
        bv0 = *(const float4*)q;
        bv1 = *(const float4*)(q + 4);
    }

    for (int s = 0; s < nS; ++s) {
        __syncthreads();
        // store staged slice to LDS (A transposed to k-major)
        AshT[ac + 0][ar] = av0.x;
        AshT[ac + 1][ar] = av0.y;
        AshT[ac + 2][ar] = av0.z;
        AshT[ac + 3][ar] = av0.w;
        AshT[ac + 4][ar] = av1.x;
        AshT[ac + 5][ar] = av1.y;
        AshT[ac + 6][ar] = av1.z;
        AshT[ac + 7][ar] = av1.w;
        *(float4*)&Bsh[bk][bf] = bv0;
        *(float4*)&Bsh[bk][bf + 4] = bv1;
        __syncthreads();

        // prefetch next slice
        if (s + 1 < nS) {
            int sn = s + 1;
            int term = sn >> 3;
            int kk = (sn & 7) * 16;
            const float* T = tp.t[term];
            if (aval) {
                const float* p = T + (size_t)agr * F + kk + ac;
                av0 = *(const float4*)p;
                av1 = *(const float4*)(p + 4);
            } else {
                av0 = make_float4(0.f, 0.f, 0.f, 0.f);
                av1 = av0;
            }
            const float* q = SW + (size_t)(term0 + term) * F * F + (size_t)(kk + bk) * F + bf;
            bv0 = *(const float4*)q;
            bv1 = *(const float4*)(q + 4);
        }

        // compute 16 k-steps on the LDS tile
#pragma unroll
        for (int k = 0; k < 16; ++k) {
            float4 a0 = *(const float4*)&AshT[k][ty * 8];
            float4 a1 = *(const float4*)&AshT[k][ty * 8 + 4];
            float4 b0 = *(const float4*)&Bsh[k][tx * 8];
            float4 b1 = *(const float4*)&Bsh[k][tx * 8 + 4];
            float a[8] = {a0.x, a0.y, a0.z, a0.w, a1.x, a1.y, a1.z, a1.w};
            float b[8] = {b0.x, b0.y, b0.z, b0.w, b1.x, b1.y, b1.z, b1.w};
#pragma unroll
            for (int ri = 0; ri < 8; ri++)
#pragma unroll
                for (int ci = 0; ci < 8; ci++) acc[ri][ci] += a[ri] * b[ci];
        }
    }

    // epilogue: out = (first ? bias : out) + acc, float4 stores
#pragma unroll
    for (int ri = 0; ri < 8; ri++) {
        int gr = n0 + ty * 8 + ri;
        if (gr < n) {
            float* orow = out + (size_t)gr * F + tx * 8;
            float4 v0, v1;
            if (first) {
                const float4 bb0 = *(const float4*)(bias + tx * 8);
                const float4 bb1 = *(const float4*)(bias + tx * 8 + 4);
                v0 = bb0; v1 = bb1;
            } else {
                v0 = *(const float4*)orow;
                v1 = *(const float4*)(orow + 4);
            }
            v0.x += acc[ri][0]; v0.y += acc[ri][1]; v0.z += acc[ri][2]; v0.w += acc[ri][3];
            v1.x += acc[ri][4]; v1.y += acc[ri][5]; v1.z += acc[ri][6]; v1.w += acc[ri][7];
            *(float4*)orow = v0;
            *(float4*)(orow + 4) = v1;
        }
    }
}

// ---------------- launch ----------------

extern "C" void kernel_launch(void* const* d_in, const int* in_sizes, int n_in,
                              void* d_out, int out_size, void* d_ws, size_t ws_size,
                              hipStream_t stream) {
    const float* input = (const float*)d_in[0];
    const int* esrc = (const int*)d_in[1];
    const int* edst = (const int*)d_in[2];
    const float* ew = (const float*)d_in[3];
    const float* SW = (const float*)d_in[4];
    const float* bias = (const float*)d_in[5];
    float* out = (float*)d_out;

    int N = in_sizes[0] / F;
    int E = in_sizes[1];

    size_t off = 0;
    auto take = [&](size_t bytes) -> void* {
        void* p = (char*)d_ws + off;
        off += (bytes + 255) & ~(size_t)255;
        return p;
    };
    int* counts = (int*)take((size_t)N * 4);
    int* offsets = (int*)take((size_t)(N + 1) * 4);
    int* cursor = (int*)take((size_t)N * 4);
    int* partials = (int*)take(4096);
    int* ssrc = (int*)take((size_t)E * 4);
    float* swt = (float*)take((size_t)E * 4);

    size_t term_aligned = (((size_t)N * F * 4) + 255) & ~(size_t)255;
    size_t need_full = off + 7 * term_aligned;
    bool full = ws_size >= need_full;

    hipMemsetAsync(counts, 0, (size_t)N * 4, stream);

    int eb = (E + 255) / 256;
    int nb = (N + 255) / 256;
    count_kernel<<<eb, 256, 0, stream>>>(edst, counts, E);
    scan_partial<<<nb, 256, 0, stream>>>(counts, partials, N);
    scan_root<<<1, 64, 0, stream>>>(partials, nb);
    scan_final<<<nb, 256, 0, stream>>>(counts, partials, offsets, cursor, N);
    fill_kernel<<<eb, 256, 0, stream>>>(esrc, edst, ew, cursor, ssrc, swt, E);

    int gemm_blocks = (N + 127) / 128;
    int spmm_blocks = (N + 3) / 4;

    if (full) {
        // materialize terms 1..7, then one K=1024 GEMM
        TPtrs tp;
        tp.t[0] = input;
        for (int i = 1; i < 8; i++) tp.t[i] = (float*)take(term_aligned);
        const float* cur = input;
        for (int i = 1; i < 8; i++) {
            float* nxt = (float*)tp.t[i];
            spmm_kernel<<<spmm_blocks, 256, 0, stream>>>(offsets, ssrc, swt, cur, nxt, N);
            cur = nxt;
        }
        gemm_multi<<<gemm_blocks, 256, 0, stream>>>(tp, 8, 0, SW, bias, out, N, 1);
    } else {
        // fallback: ping/pong terms, accumulate into out per term
        float* ping = (float*)take((size_t)N * F * 4);
        float* pong = (float*)take((size_t)N * F * 4);
        TPtrs tp;
        tp.t[0] = input;
        for (int i = 1; i < 8; i++) tp.t[i] = nullptr;
        gemm_multi<<<gemm_blocks, 256, 0, stream>>>(tp, 1, 0, SW, bias, out, N, 1);
        const float* cur = input;
        float* bufs[2] = {ping, pong};
        for (int i = 1; i < 8; i++) {
            float* nxt = bufs[(i - 1) & 1];
            spmm_kernel<<<spmm_blocks, 256, 0, stream>>>(offsets, ssrc, swt, cur, nxt, N);
            TPtrs tpi;
            tpi.t[0] = nxt;
            for (int j = 1; j < 8; j++) tpi.t[j] = nullptr;
            gemm_multi<<<gemm_blocks, 256, 0, stream>>>(tpi, 1, i, SW, bias, out, N, 0);
            cur = nxt;
        }
    }
}

// Round 3
// 427.221 us; speedup vs baseline: 3.0067x; 1.7231x over previous
//
#include <hip/hip_runtime.h>
#include <hip/hip_bf16.h>

// truncated_krylov_layer: out = concat(X, AX, ..., A^7 X) @ W + b
//  - CSR-by-dst build (count/scan/fill) in workspace.
//  - Terms kept in bf16: halves SpMM gather traffic and enables MFMA GEMM.
//  - 7 SpMM passes, wave-per-dst-row, 1 uint (bf16x2)/lane, fp32 accumulate.
//  - GEMM: single K=1024 bf16 MFMA GEMM (mfma_f32_16x16x32_bf16),
//    128x128 tile, 4 waves x 4x4 16x16 tiles, global_load_lds width-16
//    staging, XOR chunk swizzle for 2-way-max LDS bank aliasing.
//  - W pre-transposed+converted to bf16 Wt[8][n][k] once per launch.

#define F 128

typedef __attribute__((ext_vector_type(8))) short short8;
typedef __attribute__((ext_vector_type(4))) float float4v;

__device__ __forceinline__ unsigned short f2bf(float f) {
    unsigned int u = __float_as_uint(f);
    unsigned int r = (u + 0x7fffu + ((u >> 16) & 1u)) >> 16;
    return (unsigned short)r;
}

__device__ __forceinline__ void gload_lds16(const void* g, void* l) {
    __builtin_amdgcn_global_load_lds((__attribute__((address_space(1))) void*)g,
                                     (__attribute__((address_space(3))) void*)l, 16, 0, 0);
}

// ---------------- CSR build ----------------

__global__ __launch_bounds__(256) void count_kernel(const int* __restrict__ dst,
                                                    int* __restrict__ counts, int E) {
    int e = blockIdx.x * 256 + threadIdx.x;
    if (e < E) atomicAdd(&counts[dst[e]], 1);
}

__global__ __launch_bounds__(256) void scan_partial(const int* __restrict__ counts,
                                                    int* __restrict__ partials, int n) {
    __shared__ int sm[256];
    int tid = threadIdx.x;
    int i = blockIdx.x * 256 + tid;
    sm[tid] = (i < n) ? counts[i] : 0;
    __syncthreads();
    for (int off = 128; off > 0; off >>= 1) {
        if (tid < off) sm[tid] += sm[tid + off];
        __syncthreads();
    }
    if (tid == 0) partials[blockIdx.x] = sm[0];
}

__global__ __launch_bounds__(64) void scan_root(int* __restrict__ partials, int nb) {
    int lane = threadIdx.x;
    int run = 0;
    for (int base = 0; base < nb; base += 64) {
        int i = base + lane;
        int v = (i < nb) ? partials[i] : 0;
        int orig = v;
        for (int off = 1; off < 64; off <<= 1) {
            int t = __shfl_up(v, off, 64);
            if (lane >= off) v += t;
        }
        if (i < nb) partials[i] = run + v - orig;  // exclusive
        run += __shfl(v, 63, 64);
    }
}

__global__ __launch_bounds__(256) void scan_final(const int* __restrict__ counts,
                                                  const int* __restrict__ partials,
                                                  int* __restrict__ offsets,
                                                  int* __restrict__ cursor, int n) {
    __shared__ int sm[256];
    int tid = threadIdx.x;
    int i = blockIdx.x * 256 + tid;
    int v = (i < n) ? counts[i] : 0;
    sm[tid] = v;
    __syncthreads();
    for (int off = 1; off < 256; off <<= 1) {
        int t = (tid >= off) ? sm[tid - off] : 0;
        __syncthreads();
        sm[tid] += t;
        __syncthreads();
    }
    int incl = sm[tid];
    int base = partials[blockIdx.x];
    if (i < n) {
        offsets[i + 1] = base + incl;
        cursor[i] = base + incl - v;
    }
    if (i == 0) offsets[0] = 0;
}

__global__ __launch_bounds__(256) void fill_kernel(const int* __restrict__ src,
                                                   const int* __restrict__ dst,
                                                   const float* __restrict__ w,
                                                   int* __restrict__ cursor,
                                                   int* __restrict__ ssrc,
                                                   float* __restrict__ swt, int E) {
    int e = blockIdx.x * 256 + threadIdx.x;
    if (e < E) {
        int d = dst[e];
        int pos = atomicAdd(&cursor[d], 1);
        ssrc[pos] = src[e];
        swt[pos] = w[e];
    }
}

// ---------------- converts ----------------

__global__ __launch_bounds__(256) void convert_input(const float* __restrict__ X,
                                                     unsigned int* __restrict__ Y, int n2) {
    int i = blockIdx.x * 256 + threadIdx.x;
    if (i < n2) {
        float2 v = ((const float2*)X)[i];
        Y[i] = (unsigned int)f2bf(v.x) | ((unsigned int)f2bf(v.y) << 16);
    }
}

// SW[1024][128] (row = t*128+k, col = n) -> Wt[t][n][k] bf16
__global__ __launch_bounds__(256) void convert_wt(const float* __restrict__ SW,
                                                  unsigned short* __restrict__ Wt) {
    int i = blockIdx.x * 256 + threadIdx.x;  // 131072
    int r = i >> 7, c = i & 127;
    int t = r >> 7, k = r & 127;
    Wt[t * 16384 + c * 128 + k] = f2bf(SW[i]);
}

// ---------------- SpMM (bf16): one wave per dst row ----------------

__global__ __launch_bounds__(256) void spmm_bf16(const int* __restrict__ offs,
                                                 const int* __restrict__ ssrc,
                                                 const float* __restrict__ swt,
                                                 const unsigned int* __restrict__ Xu,
                                                 unsigned int* __restrict__ Yu, int n) {
    int gw = (int)((blockIdx.x * 256 + threadIdx.x) >> 6);
    int lane = threadIdx.x & 63;
    if (gw >= n) return;
    int s0 = offs[gw], s1 = offs[gw + 1];
    float ax = 0.f, ay = 0.f;
    for (int base = s0; base < s1; base += 64) {
        int cnt = min(s1 - base, 64);
        int sv = 0;
        float wv = 0.f;
        if (lane < cnt) {
            sv = ssrc[base + lane];
            wv = swt[base + lane];
        }
        int j = 0;
        int jm = cnt & ~3;
        for (; j < jm; j += 4) {
            int a0 = __shfl(sv, j, 64), a1 = __shfl(sv, j + 1, 64);
            int a2 = __shfl(sv, j + 2, 64), a3 = __shfl(sv, j + 3, 64);
            float w0 = __shfl(wv, j, 64), w1 = __shfl(wv, j + 1, 64);
            float w2 = __shfl(wv, j + 2, 64), w3 = __shfl(wv, j + 3, 64);
            unsigned int u0 = Xu[(size_t)a0 * 64 + lane];
            unsigned int u1 = Xu[(size_t)a1 * 64 + lane];
            unsigned int u2 = Xu[(size_t)a2 * 64 + lane];
            unsigned int u3 = Xu[(size_t)a3 * 64 + lane];
            ax += w0 * __uint_as_float(u0 << 16); ay += w0 * __uint_as_float(u0 & 0xffff0000u);
            ax += w1 * __uint_as_float(u1 << 16); ay += w1 * __uint_as_float(u1 & 0xffff0000u);
            ax += w2 * __uint_as_float(u2 << 16); ay += w2 * __uint_as_float(u2 & 0xffff0000u);
            ax += w3 * __uint_as_float(u3 << 16); ay += w3 * __uint_as_float(u3 & 0xffff0000u);
        }
        for (; j < cnt; ++j) {
            int a = __shfl(sv, j, 64);
            float wj = __shfl(wv, j, 64);
            unsigned int u = Xu[(size_t)a * 64 + lane];
            ax += wj * __uint_as_float(u << 16);
            ay += wj * __uint_as_float(u & 0xffff0000u);
        }
    }
    Yu[(size_t)gw * 64 + lane] = (unsigned int)f2bf(ax) | ((unsigned int)f2bf(ay) << 16);
}

// ---------------- bf16 MFMA GEMM: out[n,128] = cat(T0..T7) @ W + bias ----------------
// Terms bf16 [N][128]; Wt bf16 [8][n][k] (pre-transposed). 128x128 block tile,
// 256 threads = 4 waves in 2x2, each wave computes 64x64 via 4x4 mfma 16x16x32.
// LDS tiles As/Bs: [128 rows][64 k] bf16 = 16 KB each, 16B-chunk XOR swizzle
// (phys_chunk = logical_chunk ^ (row & 7)) -> 2-way max bank aliasing.

struct TermPtrs { const unsigned short* t[8]; };

__global__ __launch_bounds__(256) void gemm_bf16(TermPtrs tp,
                                                 const unsigned short* __restrict__ Wt,
                                                 const float* __restrict__ bias,
                                                 float* __restrict__ out, int n) {
    __shared__ unsigned short As[128 * 64];
    __shared__ unsigned short Bs[128 * 64];
    int tid = threadIdx.x;
    int w = tid >> 6;
    int lane = tid & 63;
    int wm = (w >> 1) * 64;
    int wn = (w & 1) * 64;
    int n0 = blockIdx.x * 128;

    float4v acc[4][4];
#pragma unroll
    for (int i = 0; i < 4; i++)
#pragma unroll
        for (int j = 0; j < 4; j++) acc[i][j] = (float4v){0.f, 0.f, 0.f, 0.f};

    // staging decomposition: each global_load_lds covers 8 rows (1 KB)
    int lr = lane >> 3;                       // row within 8-row group
    int lp = lane & 7;                        // physical 16B chunk
    int lc = lp ^ lr;                         // logical k-chunk (XOR swizzle)
    int row_a = lane & 15;                    // frag row within 16-tile
    int q = lane >> 4;                        // frag k-quad

    for (int t = 0; t < 8; ++t) {
        const unsigned short* Tt = tp.t[t];
        const unsigned short* Wtt = Wt + t * 16384;
        for (int kk = 0; kk < 128; kk += 64) {
            __syncthreads();
#pragma unroll
            for (int i = 0; i < 4; ++i) {
                int r = 32 * w + 8 * i + lr;
                const unsigned short* ga = Tt + (size_t)(n0 + r) * F + kk + lc * 8;
                gload_lds16(ga, As + (32 * w + 8 * i) * 64);
                const unsigned short* gb = Wtt + (size_t)r * F + kk + lc * 8;
                gload_lds16(gb, Bs + (32 * w + 8 * i) * 64);
            }
            __syncthreads();  // compiler drains vmcnt before s_barrier
#pragma unroll
            for (int h = 0; h < 2; ++h) {
                short8 af[4], bf[4];
#pragma unroll
                for (int mi = 0; mi < 4; ++mi) {
                    int R = wm + mi * 16 + row_a;
                    int phys = (h * 4 + q) ^ (R & 7);
                    af[mi] = *(const short8*)(As + R * 64 + phys * 8);
                }
#pragma unroll
                for (int ni = 0; ni < 4; ++ni) {
                    int R = wn + ni * 16 + row_a;
                    int phys = (h * 4 + q) ^ (R & 7);
                    bf[ni] = *(const short8*)(Bs + R * 64 + phys * 8);
                }
#pragma unroll
                for (int mi = 0; mi < 4; ++mi)
#pragma unroll
                    for (int ni = 0; ni < 4; ++ni)
                        acc[mi][ni] = __builtin_amdgcn_mfma_f32_16x16x32_bf16(
                            af[mi], bf[ni], acc[mi][ni], 0, 0, 0);
            }
        }
    }

    // epilogue: C/D layout col=lane&15, row=(lane>>4)*4+reg
    int col_l = lane & 15;
    int rq = lane >> 4;
#pragma unroll
    for (int ni = 0; ni < 4; ++ni) {
        float bcol = bias[wn + ni * 16 + col_l];
#pragma unroll
        for (int mi = 0; mi < 4; ++mi) {
#pragma unroll
            for (int r = 0; r < 4; ++r) {
                int gr = n0 + wm + mi * 16 + rq * 4 + r;
                if (gr < n) out[(size_t)gr * F + wn + ni * 16 + col_l] = acc[mi][ni][r] + bcol;
            }
        }
    }
}

// ---------------- launch ----------------

extern "C" void kernel_launch(void* const* d_in, const int* in_sizes, int n_in,
                              void* d_out, int out_size, void* d_ws, size_t ws_size,
                              hipStream_t stream) {
    const float* input = (const float*)d_in[0];
    const int* esrc = (const int*)d_in[1];
    const int* edst = (const int*)d_in[2];
    const float* ew = (const float*)d_in[3];
    const float* SW = (const float*)d_in[4];
    const float* bias = (const float*)d_in[5];
    float* out = (float*)d_out;

    int N = in_sizes[0] / F;
    int E = in_sizes[1];

    size_t off = 0;
    auto take = [&](size_t bytes) -> void* {
        void* p = (char*)d_ws + off;
        off += (bytes + 255) & ~(size_t)255;
        return p;
    };
    int* counts = (int*)take((size_t)N * 4);
    int* offsets = (int*)take((size_t)(N + 1) * 4);
    int* cursor = (int*)take((size_t)N * 4);
    int* partials = (int*)take(4096);
    int* ssrc = (int*)take((size_t)E * 4);
    float* swt = (float*)take((size_t)E * 4);
    unsigned short* Wt = (unsigned short*)take((size_t)8 * 128 * 128 * 2);

    // bf16 term buffers, padded by 128 rows for GEMM tile overreads
    size_t term_bytes = (size_t)(N + 128) * F * 2;
    unsigned short* Xbf = (unsigned short*)take(term_bytes);
    TermPtrs tp;
    tp.t[0] = Xbf;
    for (int i = 1; i < 8; i++) tp.t[i] = (unsigned short*)take(term_bytes);
    (void)ws_size;

    hipMemsetAsync(counts, 0, (size_t)N * 4, stream);

    int eb = (E + 255) / 256;
    int nb = (N + 255) / 256;
    int n2 = N * (F / 2);

    convert_input<<<(n2 + 255) / 256, 256, 0, stream>>>(input, (unsigned int*)Xbf, n2);
    convert_wt<<<512, 256, 0, stream>>>(SW, Wt);

    count_kernel<<<eb, 256, 0, stream>>>(edst, counts, E);
    scan_partial<<<nb, 256, 0, stream>>>(counts, partials, N);
    scan_root<<<1, 64, 0, stream>>>(partials, nb);
    scan_final<<<nb, 256, 0, stream>>>(counts, partials, offsets, cursor, N);
    fill_kernel<<<eb, 256, 0, stream>>>(esrc, edst, ew, cursor, ssrc, swt, E);

    int spmm_blocks = (N + 3) / 4;
    for (int i = 1; i < 8; i++) {
        spmm_bf16<<<spmm_blocks, 256, 0, stream>>>(offsets, ssrc, swt,
                                                   (const unsigned int*)tp.t[i - 1],
                                                   (unsigned int*)tp.t[i], N);
    }

    int gemm_blocks = (N + 127) / 128;
    gemm_bf16<<<gemm_blocks, 256, 0, stream>>>(tp, Wt, bias, out, N);
}

// Round 4
// 399.271 us; speedup vs baseline: 3.2172x; 1.0700x over previous
//
#include <hip/hip_runtime.h>
#include <hip/hip_bf16.h>

// truncated_krylov_layer: out = concat(X, AX, ..., A^7 X) @ W + b
//  - CSR-by-dst build (count/scan/fill) in workspace; fill stores (src,w)
//    as one int2 (halves scatter-line traffic vs two 4B stores).
//  - Terms in bf16. 7 SpMM passes: one wave per dst row, 32 lanes/row
//    (uint2 = 4 bf16 per lane), 2 edges processed per gather instruction
//    (half-wave split), 8-edge unroll, fp32 accumulate, shfl edge broadcast.
//  - GEMM: single K=1024 bf16 MFMA GEMM (mfma_f32_16x16x32_bf16),
//    128x128 tile, global_load_lds width-16 staging, XOR chunk swizzle.
//  - W pre-transposed+converted to bf16 Wt[8][n][k] once per launch.

#define F 128

typedef __attribute__((ext_vector_type(8))) short short8;
typedef __attribute__((ext_vector_type(4))) float float4v;

__device__ __forceinline__ unsigned short f2bf(float f) {
    unsigned int u = __float_as_uint(f);
    unsigned int r = (u + 0x7fffu + ((u >> 16) & 1u)) >> 16;
    return (unsigned short)r;
}

__device__ __forceinline__ float bf_lo(unsigned int u) { return __uint_as_float(u << 16); }
__device__ __forceinline__ float bf_hi(unsigned int u) { return __uint_as_float(u & 0xffff0000u); }

__device__ __forceinline__ void gload_lds16(const void* g, void* l) {
    __builtin_amdgcn_global_load_lds((__attribute__((address_space(1))) void*)g,
                                     (__attribute__((address_space(3))) void*)l, 16, 0, 0);
}

// ---------------- CSR build ----------------

__global__ __launch_bounds__(256) void count_kernel(const int* __restrict__ dst,
                                                    int* __restrict__ counts, int E) {
    int e = blockIdx.x * 256 + threadIdx.x;
    if (e < E) atomicAdd(&counts[dst[e]], 1);
}

__global__ __launch_bounds__(256) void scan_partial(const int* __restrict__ counts,
                                                    int* __restrict__ partials, int n) {
    __shared__ int sm[256];
    int tid = threadIdx.x;
    int i = blockIdx.x * 256 + tid;
    sm[tid] = (i < n) ? counts[i] : 0;
    __syncthreads();
    for (int off = 128; off > 0; off >>= 1) {
        if (tid < off) sm[tid] += sm[tid + off];
        __syncthreads();
    }
    if (tid == 0) partials[blockIdx.x] = sm[0];
}

__global__ __launch_bounds__(64) void scan_root(int* __restrict__ partials, int nb) {
    int lane = threadIdx.x;
    int run = 0;
    for (int base = 0; base < nb; base += 64) {
        int i = base + lane;
        int v = (i < nb) ? partials[i] : 0;
        int orig = v;
        for (int off = 1; off < 64; off <<= 1) {
            int t = __shfl_up(v, off, 64);
            if (lane >= off) v += t;
        }
        if (i < nb) partials[i] = run + v - orig;  // exclusive
        run += __shfl(v, 63, 64);
    }
}

__global__ __launch_bounds__(256) void scan_final(const int* __restrict__ counts,
                                                  const int* __restrict__ partials,
                                                  int* __restrict__ offsets,
                                                  int* __restrict__ cursor, int n) {
    __shared__ int sm[256];
    int tid = threadIdx.x;
    int i = blockIdx.x * 256 + tid;
    int v = (i < n) ? counts[i] : 0;
    sm[tid] = v;
    __syncthreads();
    for (int off = 1; off < 256; off <<= 1) {
        int t = (tid >= off) ? sm[tid - off] : 0;
        __syncthreads();
        sm[tid] += t;
        __syncthreads();
    }
    int incl = sm[tid];
    int base = partials[blockIdx.x];
    if (i < n) {
        offsets[i + 1] = base + incl;
        cursor[i] = base + incl - v;
    }
    if (i == 0) offsets[0] = 0;
}

__global__ __launch_bounds__(256) void fill_kernel(const int* __restrict__ src,
                                                   const int* __restrict__ dst,
                                                   const float* __restrict__ w,
                                                   int* __restrict__ cursor,
                                                   int2* __restrict__ sedge, int E) {
    int e = blockIdx.x * 256 + threadIdx.x;
    if (e < E) {
        int d = dst[e];
        int pos = atomicAdd(&cursor[d], 1);
        int2 v;
        v.x = src[e];
        v.y = __float_as_int(w[e]);
        sedge[pos] = v;
    }
}

// ---------------- converts ----------------

__global__ __launch_bounds__(256) void convert_input(const float* __restrict__ X,
                                                     unsigned int* __restrict__ Y, int n2) {
    int i = blockIdx.x * 256 + threadIdx.x;
    if (i < n2) {
        float2 v = ((const float2*)X)[i];
        Y[i] = (unsigned int)f2bf(v.x) | ((unsigned int)f2bf(v.y) << 16);
    }
}

// SW[1024][128] (row = t*128+k, col = n) -> Wt[t][n][k] bf16
__global__ __launch_bounds__(256) void convert_wt(const float* __restrict__ SW,
                                                  unsigned short* __restrict__ Wt) {
    int i = blockIdx.x * 256 + threadIdx.x;  // 131072
    int r = i >> 7, c = i & 127;
    int t = r >> 7, k = r & 127;
    Wt[t * 16384 + c * 128 + k] = f2bf(SW[i]);
}

// ---------------- SpMM (bf16): one wave per dst row, 2 edges in parallel --------
// Row = 32 uint2 (4 bf16/lane). Lanes 0-31 process even edge of a pair, lanes
// 32-63 the odd edge; final combine via one shfl. 8-edge unroll -> 4 gathers
// in flight per wave.

__global__ __launch_bounds__(256) void spmm_bf16(const int* __restrict__ offs,
                                                 const int2* __restrict__ sedge,
                                                 const uint2* __restrict__ Xu,
                                                 uint2* __restrict__ Yu, int n) {
    int gw = (int)((blockIdx.x * 256 + threadIdx.x) >> 6);
    int lane = threadIdx.x & 63;
    if (gw >= n) return;
    int half = lane >> 5;   // 0: even edges, 1: odd edges
    int sl = lane & 31;     // uint2 index within row
    int s0 = offs[gw], s1 = offs[gw + 1];
    float a0 = 0.f, a1 = 0.f, a2 = 0.f, a3 = 0.f;

    for (int base = s0; base < s1; base += 64) {
        int cnt = min(s1 - base, 64);
        int sv = 0;
        float wv = 0.f;
        if (lane < cnt) {
            int2 e = sedge[base + lane];
            sv = e.x;
            wv = __int_as_float(e.y);
        }
        for (int j = 0; j < cnt; j += 8) {
            int i0 = j + half, i1 = j + 2 + half, i2 = j + 4 + half, i3 = j + 6 + half;
            int src0 = __shfl(sv, i0, 64); float w0 = __shfl(wv, i0, 64);
            int src1 = __shfl(sv, i1, 64); float w1 = __shfl(wv, i1, 64);
            int src2 = __shfl(sv, i2, 64); float w2 = __shfl(wv, i2, 64);
            int src3 = __shfl(sv, i3, 64); float w3 = __shfl(wv, i3, 64);
            uint2 u0 = Xu[(size_t)src0 * 32 + sl];
            uint2 u1 = Xu[(size_t)src1 * 32 + sl];
            uint2 u2 = Xu[(size_t)src2 * 32 + sl];
            uint2 u3 = Xu[(size_t)src3 * 32 + sl];
            a0 += w0 * bf_lo(u0.x); a1 += w0 * bf_hi(u0.x);
            a2 += w0 * bf_lo(u0.y); a3 += w0 * bf_hi(u0.y);
            a0 += w1 * bf_lo(u1.x); a1 += w1 * bf_hi(u1.x);
            a2 += w1 * bf_lo(u1.y); a3 += w1 * bf_hi(u1.y);
            a0 += w2 * bf_lo(u2.x); a1 += w2 * bf_hi(u2.x);
            a2 += w2 * bf_lo(u2.y); a3 += w2 * bf_hi(u2.y);
            a0 += w3 * bf_lo(u3.x); a1 += w3 * bf_hi(u3.x);
            a2 += w3 * bf_lo(u3.y); a3 += w3 * bf_hi(u3.y);
        }
    }

    // combine odd-edge half into even-edge half
    a0 += __shfl(a0, sl + 32, 64);
    a1 += __shfl(a1, sl + 32, 64);
    a2 += __shfl(a2, sl + 32, 64);
    a3 += __shfl(a3, sl + 32, 64);
    if (half == 0) {
        uint2 r;
        r.x = (unsigned int)f2bf(a0) | ((unsigned int)f2bf(a1) << 16);
        r.y = (unsigned int)f2bf(a2) | ((unsigned int)f2bf(a3) << 16);
        Yu[(size_t)gw * 32 + sl] = r;
    }
}

// ---------------- bf16 MFMA GEMM: out[n,128] = cat(T0..T7) @ W + bias ----------------

struct TermPtrs { const unsigned short* t[8]; };

__global__ __launch_bounds__(256) void gemm_bf16(TermPtrs tp,
                                                 const unsigned short* __restrict__ Wt,
                                                 const float* __restrict__ bias,
                                                 float* __restrict__ out, int n) {
    __shared__ unsigned short As[128 * 64];
    __shared__ unsigned short Bs[128 * 64];
    int tid = threadIdx.x;
    int w = tid >> 6;
    int lane = tid & 63;
    int wm = (w >> 1) * 64;
    int wn = (w & 1) * 64;
    int n0 = blockIdx.x * 128;

    float4v acc[4][4];
#pragma unroll
    for (int i = 0; i < 4; i++)
#pragma unroll
        for (int j = 0; j < 4; j++) acc[i][j] = (float4v){0.f, 0.f, 0.f, 0.f};

    int lr = lane >> 3;
    int lp = lane & 7;
    int lc = lp ^ lr;       // XOR chunk swizzle
    int row_a = lane & 15;
    int q = lane >> 4;

    for (int t = 0; t < 8; ++t) {
        const unsigned short* Tt = tp.t[t];
        const unsigned short* Wtt = Wt + t * 16384;
        for (int kk = 0; kk < 128; kk += 64) {
            __syncthreads();
#pragma unroll
            for (int i = 0; i < 4; ++i) {
                int r = 32 * w + 8 * i + lr;
                const unsigned short* ga = Tt + (size_t)(n0 + r) * F + kk + lc * 8;
                gload_lds16(ga, As + (32 * w + 8 * i) * 64);
                const unsigned short* gb = Wtt + (size_t)r * F + kk + lc * 8;
                gload_lds16(gb, Bs + (32 * w + 8 * i) * 64);
            }
            __syncthreads();
#pragma unroll
            for (int h = 0; h < 2; ++h) {
                short8 af[4], bf[4];
#pragma unroll
                for (int mi = 0; mi < 4; ++mi) {
                    int R = wm + mi * 16 + row_a;
                    int phys = (h * 4 + q) ^ (R & 7);
                    af[mi] = *(const short8*)(As + R * 64 + phys * 8);
                }
#pragma unroll
                for (int ni = 0; ni < 4; ++ni) {
                    int R = wn + ni * 16 + row_a;
                    int phys = (h * 4 + q) ^ (R & 7);
                    bf[ni] = *(const short8*)(Bs + R * 64 + phys * 8);
                }
#pragma unroll
                for (int mi = 0; mi < 4; ++mi)
#pragma unroll
                    for (int ni = 0; ni < 4; ++ni)
                        acc[mi][ni] = __builtin_amdgcn_mfma_f32_16x16x32_bf16(
                            af[mi], bf[ni], acc[mi][ni], 0, 0, 0);
            }
        }
    }

    // epilogue: C/D layout col=lane&15, row=(lane>>4)*4+reg
    int col_l = lane & 15;
    int rq = lane >> 4;
#pragma unroll
    for (int ni = 0; ni < 4; ++ni) {
        float bcol = bias[wn + ni * 16 + col_l];
#pragma unroll
        for (int mi = 0; mi < 4; ++mi) {
#pragma unroll
            for (int r = 0; r < 4; ++r) {
                int gr = n0 + wm + mi * 16 + rq * 4 + r;
                if (gr < n) out[(size_t)gr * F + wn + ni * 16 + col_l] = acc[mi][ni][r] + bcol;
            }
        }
    }
}

// ---------------- launch ----------------

extern "C" void kernel_launch(void* const* d_in, const int* in_sizes, int n_in,
                              void* d_out, int out_size, void* d_ws, size_t ws_size,
                              hipStream_t stream) {
    const float* input = (const float*)d_in[0];
    const int* esrc = (const int*)d_in[1];
    const int* edst = (const int*)d_in[2];
    const float* ew = (const float*)d_in[3];
    const float* SW = (const float*)d_in[4];
    const float* bias = (const float*)d_in[5];
    float* out = (float*)d_out;

    int N = in_sizes[0] / F;
    int E = in_sizes[1];

    size_t off = 0;
    auto take = [&](size_t bytes) -> void* {
        void* p = (char*)d_ws + off;
        off += (bytes + 255) & ~(size_t)255;
        return p;
    };
    int* counts = (int*)take((size_t)N * 4);
    int* offsets = (int*)take((size_t)(N + 1) * 4);
    int* cursor = (int*)take((size_t)N * 4);
    int* partials = (int*)take(4096);
    int2* sedge = (int2*)take((size_t)E * 8);
    unsigned short* Wt = (unsigned short*)take((size_t)8 * 128 * 128 * 2);

    // bf16 term buffers, padded by 128 rows for GEMM tile overreads
    size_t term_bytes = (size_t)(N + 128) * F * 2;
    unsigned short* Xbf = (unsigned short*)take(term_bytes);
    TermPtrs tp;
    tp.t[0] = Xbf;
    for (int i = 1; i < 8; i++) tp.t[i] = (unsigned short*)take(term_bytes);
    (void)ws_size;

    hipMemsetAsync(counts, 0, (size_t)N * 4, stream);

    int eb = (E + 255) / 256;
    int nb = (N + 255) / 256;
    int n2 = N * (F / 2);

    convert_input<<<(n2 + 255) / 256, 256, 0, stream>>>(input, (unsigned int*)Xbf, n2);
    convert_wt<<<512, 256, 0, stream>>>(SW, Wt);

    count_kernel<<<eb, 256, 0, stream>>>(edst, counts, E);
    scan_partial<<<nb, 256, 0, stream>>>(counts, partials, N);
    scan_root<<<1, 64, 0, stream>>>(partials, nb);
    scan_final<<<nb, 256, 0, stream>>>(counts, partials, offsets, cursor, N);
    fill_kernel<<<eb, 256, 0, stream>>>(esrc, edst, ew, cursor, sedge, E);

    int spmm_blocks = (N + 3) / 4;
    for (int i = 1; i < 8; i++) {
        spmm_bf16<<<spmm_blocks, 256, 0, stream>>>(offsets, sedge,
                                                   (const uint2*)tp.t[i - 1],
                                                   (uint2*)tp.t[i], N);
    }

    int gemm_blocks = (N + 127) / 128;
    gemm_bf16<<<gemm_blocks, 256, 0, stream>>>(tp, Wt, bias, out, N);
}